// Round 10
// baseline (761.195 us; speedup 1.0000x reference)
//
#include <hip/hip_runtime.h>
#include <hip/hip_bf16.h>
#include <stdint.h>
#include <stddef.h>

// Problem sizes (fixed by the reference)
#define B_SZ 512
#define S_SZ 64
#define E_SZ 512
#define H_SZ 1024
#define V_SZ 1024
#define C_SZ 1000

typedef __hip_bfloat16 bf16;
typedef __attribute__((ext_vector_type(8))) __bf16 bf16x8;
typedef __attribute__((ext_vector_type(4))) float f32x4;

// ---- workspace layout (bytes), total 76 MB (same proven bound) ----
#define EMB_OFF   (0ull)          // emb bf16 (xproj input); REUSED as yl [512][1024] by fused
#define WIH_OFF   (1ull << 20)    // w_ih bf16 (xproj input); REUSED as y1 by fused
#define WHH_OFF   (2ull << 20)    // w_hh  bf16 [1024][1024] 2 MB
#define FC1_OFF   (4ull << 20)    // fc1_w bf16 [1024][1024] 2 MB
#define FC2_OFF   (6ull << 20)    // fc2_w bf16 [1024][1024] 2 MB (rows >=1000 zero)
#define HB_OFF    (8ull << 20)    // 4 rotating h bufs, 1 MB each; buf0 zeroed by prep
#define XP_OFF    (12ull << 20)   // x_proj bf16 [64][512][1024] 64 MB
// 16 cluster counters, 128B apart, in fc2 zero-pad rows (read only as discarded-col weights)
#define BAR_OFF   (FC2_OFF + 2048000ull)

// async global->LDS, 16B/lane; lane l lands at lds_base + l*16 (linear).
__device__ __forceinline__ void gl_lds16(const void* g, void* l) {
  __builtin_amdgcn_global_load_lds(
      (const __attribute__((address_space(1))) unsigned int*)g,
      (__attribute__((address_space(3))) unsigned int*)l, 16, 0, 0);
}

// Liveness tie (rule #17): makes the value an opaque asm output so the
// compiler CANNOT rematerialize the load inside the loop (round-8 bug:
// VGPR=96 proved breg was re-loaded from L2 every MFMA, not resident).
__device__ __forceinline__ void keep(bf16x8& v) {
  f32x4& f = reinterpret_cast<f32x4&>(v);
  asm volatile("" : "+v"(f));
}

// ---------------------------------------------------------------------------
// prep: fp32 -> bf16 weights + zero h_buf0 + zero fc2 pad rows (incl counters)
// ---------------------------------------------------------------------------
__global__ __launch_bounds__(256) void prep_kernel(
    const float* __restrict__ emb_w, const float* __restrict__ w_ih,
    const float* __restrict__ w_hh, const float* __restrict__ fc1_w,
    const float* __restrict__ fc2_w, char* __restrict__ ws) {
  bf16* emb = (bf16*)(ws + EMB_OFF);
  bf16* wih = (bf16*)(ws + WIH_OFF);
  bf16* whh = (bf16*)(ws + WHH_OFF);
  bf16* fc1 = (bf16*)(ws + FC1_OFF);
  bf16* fc2 = (bf16*)(ws + FC2_OFF);
  bf16* h0  = (bf16*)(ws + HB_OFF);

  const long N_EMB = 524288, N_WIH = 524288, N_WHH = 1048576;
  const long N_FC1 = 1048576, N_FC2 = 1048576, N_H0 = 524288;
  const long TOTAL = N_EMB + N_WIH + N_WHH + N_FC1 + N_FC2 + N_H0;

  long stride = (long)gridDim.x * blockDim.x;
  for (long i = (long)blockIdx.x * blockDim.x + threadIdx.x; i < TOTAL; i += stride) {
    long j = i;
    if (j < N_EMB) {  // row 0 forced zero (PAD row)
      emb[j] = (j < E_SZ) ? __float2bfloat16(0.f) : __float2bfloat16(emb_w[j]);
      continue;
    }
    j -= N_EMB;
    if (j < N_WIH) { wih[j] = __float2bfloat16(w_ih[j]); continue; }
    j -= N_WIH;
    if (j < N_WHH) { whh[j] = __float2bfloat16(w_hh[j]); continue; }
    j -= N_WHH;
    if (j < N_FC1) { fc1[j] = __float2bfloat16(fc1_w[j]); continue; }
    j -= N_FC1;
    if (j < N_FC2) {
      fc2[j] = (j < (long)C_SZ * H_SZ) ? __float2bfloat16(fc2_w[j]) : __float2bfloat16(0.f);
      continue;
    }
    j -= N_FC2;
    h0[j] = __float2bfloat16(0.f);
  }
}

// ---------------------------------------------------------------------------
// xproj (unchanged, proven: 46.6us, 0 bank conflicts)
// ---------------------------------------------------------------------------
__global__ __launch_bounds__(256) void xproj_kernel(
    const int* __restrict__ x_in, const float* __restrict__ b_ih,
    char* __restrict__ ws) {
  const bf16* emb = (const bf16*)(ws + EMB_OFF);
  const bf16* wih = (const bf16*)(ws + WIH_OFF);
  bf16* xp = (bf16*)(ws + XP_OFF);

  __shared__ bf16 Asm[2][128][64];
  __shared__ bf16 Bsm[2][128][64];

  const int tid = threadIdx.x;
  const int lane = tid & 63;
  const int wid = tid >> 6;
  const int mb = blockIdx.x >> 3;
  const int nb = blockIdx.x & 7;
  const int rowBase = mb * 128;
  const int colBase = nb * 128;
  const int s = rowBase >> 9;

  const int lrow = lane >> 3;
  const int lchk = lane & 7;

  int tok[4];
#pragma unroll
  for (int i = 0; i < 4; ++i) {
    int rt = wid * 32 + i * 8 + lrow;
    int b = (rowBase + rt) & 511;
    tok[i] = x_in[b * S_SZ + s];
  }

  const int wr = wid >> 1, wc = wid & 1;
  f32x4 acc[4][4];
#pragma unroll
  for (int i = 0; i < 4; ++i)
#pragma unroll
    for (int j = 0; j < 4; ++j) acc[i][j] = (f32x4){0.f, 0.f, 0.f, 0.f};

  auto stage = [&](int buf, int k0) {
#pragma unroll
    for (int i = 0; i < 4; ++i) {
      int rt = wid * 32 + i * 8;
      int sc = (lchk ^ ((rt + lrow) & 7)) * 8;
      gl_lds16(emb + (size_t)tok[i] * E_SZ + k0 + sc, &Asm[buf][rt][0]);
    }
#pragma unroll
    for (int i = 0; i < 4; ++i) {
      int rt = wid * 32 + i * 8;
      int sc = (lchk ^ ((rt + lrow) & 7)) * 8;
      gl_lds16(wih + (size_t)(colBase + rt + lrow) * E_SZ + k0 + sc, &Bsm[buf][rt][0]);
    }
  };

  stage(0, 0);
  __syncthreads();
  int cur = 0;
  for (int t8 = 0; t8 < 8; ++t8) {
    if (t8 < 7) stage(cur ^ 1, (t8 + 1) * 64);
#pragma unroll
    for (int kk = 0; kk < 2; ++kk) {
      const int kfc = kk * 4 + (lane >> 4);
      bf16x8 a[4], b[4];
#pragma unroll
      for (int i = 0; i < 4; ++i) {
        int r = wr * 64 + i * 16 + (lane & 15);
        a[i] = *(const bf16x8*)&Asm[cur][r][(kfc ^ (r & 7)) * 8];
      }
#pragma unroll
      for (int j = 0; j < 4; ++j) {
        int r = wc * 64 + j * 16 + (lane & 15);
        b[j] = *(const bf16x8*)&Bsm[cur][r][(kfc ^ (r & 7)) * 8];
      }
#pragma unroll
      for (int i = 0; i < 4; ++i)
#pragma unroll
        for (int j = 0; j < 4; ++j)
          acc[i][j] = __builtin_amdgcn_mfma_f32_16x16x32_bf16(a[i], b[j], acc[i][j], 0, 0, 0);
    }
    __syncthreads();
    cur ^= 1;
  }

  const int crow = (lane >> 4) * 4;
  const int ccol = lane & 15;
#pragma unroll
  for (int j = 0; j < 4; ++j) {
    const int col = colBase + wc * 64 + j * 16 + ccol;
    const float bias = b_ih[col];
#pragma unroll
    for (int i = 0; i < 4; ++i) {
      const int r0 = rowBase + wr * 64 + i * 16 + crow;
#pragma unroll
      for (int reg = 0; reg < 4; ++reg) {
        float v = acc[i][j][reg] + bias;
        xp[(size_t)(r0 + reg) * H_SZ + col] = __float2bfloat16(v);
      }
    }
  }
}

// ---------------------------------------------------------------------------
// Cluster barrier (fan-in 16) — byte-identical mechanics to rounds 6-8 (proven).
// ---------------------------------------------------------------------------
__device__ __forceinline__ void clusterbar(unsigned* bar, unsigned target, bool acq) {
  __syncthreads();
  if (threadIdx.x == 0) {
    __hip_atomic_fetch_add(bar, 1u, __ATOMIC_RELEASE, __HIP_MEMORY_SCOPE_AGENT);
    while (__hip_atomic_load(bar, __ATOMIC_RELAXED, __HIP_MEMORY_SCOPE_AGENT) < target)
      __builtin_amdgcn_s_sleep(1);
    if (acq)
      (void)__hip_atomic_load(bar, __ATOMIC_ACQUIRE, __HIP_MEMORY_SCOPE_AGENT);
  }
  asm volatile("" ::: "memory");
  __syncthreads();
}

// ---------------------------------------------------------------------------
// Load this thread's 32 B-fragments (out-col c0, all K=1024) into registers.
// (m89/r8-proven layout.) keep() forces true residency.
// ---------------------------------------------------------------------------
__device__ __forceinline__ void load_breg(bf16x8 (&breg)[16][2],
                                          const bf16* w, int c0, int lane) {
  const bf16* wrow = w + (size_t)c0 * H_SZ + ((lane >> 4) << 3);
#pragma unroll
  for (int i = 0; i < 16; ++i)
#pragma unroll
    for (int kk = 0; kk < 2; ++kk) {
      breg[i][kk] = *(const bf16x8*)(wrow + i * 64 + kk * 32);
      keep(breg[i][kk]);
    }
}

// ---------------------------------------------------------------------------
// phase v3: one 32x64 tile, 8 waves (wr=wid&1 rowhalf, wc=wid>>1 col quarter).
// WHOLE A tile (32 rows x K=1024 = 64 fragment-packed KB) staged in ONE
// vmcnt(0)+s_barrier round: 64 frags x 1KB, 8 gl_lds16 per wave, fully
// pipelined. Then 32 ds_read_b128 (stride-1, zero conflicts) + 32 MFMA per
// wave with no further syncs. B entirely from resident registers.
// Round-8's 16 barrier rounds -> 1. MODE 0: RNN; 1: FC1 relu; 2: FC2 fp32.
// ---------------------------------------------------------------------------
template <int MODE>
__device__ __forceinline__ void phase(
    const bf16* __restrict__ Asrc, const bf16x8 (&breg)[16][2], bf16* Ap,
    int lane, int wid, int rowBase, float bias_v,
    const bf16 (&xv)[4], const int (&lenv)[4], int t, int r0, int c0,
    bf16* __restrict__ dst, bf16* __restrict__ yl, float* __restrict__ outf) {
  const int lr = lane & 15;         // row within 16-row half
  const int lk = (lane >> 4) << 3;  // 8-elem k sub-offset
  const int fbase = wid * 8;        // this wave's 8 fragments

#pragma unroll
  for (int o = 0; o < 8; ++o) {
    const int f = fbase + o;             // f = rowhalf*32 + kchunk
    const int rowhalf = f >> 5;
    const int kchunk = f & 31;
    const bf16* g = Asrc + (size_t)(rowBase + rowhalf * 16 + lr) * H_SZ +
                    kchunk * 32 + lk;
    gl_lds16(g, Ap + f * 512);           // linear lane-major = fragment layout
  }
  asm volatile("s_waitcnt vmcnt(0)" ::: "memory");
  __builtin_amdgcn_s_barrier();
  __builtin_amdgcn_sched_barrier(0);

  const int wr = wid & 1;
  f32x4 acc = (f32x4){0.f, 0.f, 0.f, 0.f};
  const bf16* Abase = Ap + (wr * 32) * 512 + lane * 8;
#pragma unroll
  for (int i = 0; i < 16; ++i) {
    bf16x8 a0 = *(const bf16x8*)(Abase + (2 * i) * 512);
    bf16x8 a1 = *(const bf16x8*)(Abase + (2 * i + 1) * 512);
    acc = __builtin_amdgcn_mfma_f32_16x16x32_bf16(a0, breg[i][0], acc, 0, 0, 0);
    acc = __builtin_amdgcn_mfma_f32_16x16x32_bf16(a1, breg[i][1], acc, 0, 0, 0);
  }

  // epilogue (D map: col=lane&15, row=(lane>>4)*4+reg — m89-verified)
#pragma unroll
  for (int reg = 0; reg < 4; ++reg) {
    const int row = r0 + reg;
    float v = acc[reg];
    if constexpr (MODE == 0) {
      v += bias_v + __bfloat162float(xv[reg]);
      v = fminf(fmaxf(v, -15.f), 15.f);      // overflow guard for fast tanh
      float e = __expf(2.f * v);
      float h = (e - 1.f) / (e + 1.f);
      bf16 hb = __float2bfloat16(h);
      dst[(size_t)row * H_SZ + c0] = hb;
      if (t == lenv[reg] - 1) yl[(size_t)row * H_SZ + c0] = hb;
    } else if constexpr (MODE == 1) {
      dst[(size_t)row * H_SZ + c0] = __float2bfloat16(fmaxf(v + bias_v, 0.f));
    } else {
      if (c0 < C_SZ) outf[(size_t)row * C_SZ + c0] = v + bias_v;
    }
  }
}

// ---------------------------------------------------------------------------
// rnn_fused: 64 steps + FC1 + FC2, ONE dispatch, grid 256 x 512thr.
// Register-resident B (keep()-forced), whole-A single-barrier staging (64KB
// LDS), 4-buf h rotation + acquire-every-4 + cluster barrier: unchanged
// (proven rounds 6-8). XCD-aligned clusters: mb=(bid&7)*2+((bid>>3)&1).
// ---------------------------------------------------------------------------
__global__ __launch_bounds__(512, 2) void rnn_fused_kernel(
    const float* __restrict__ b_hh, const float* __restrict__ fc1_b,
    const float* __restrict__ fc2_b, const int* __restrict__ lens,
    char* __restrict__ ws, float* __restrict__ out) {
  __shared__ bf16 Ap[32768];  // 64 frags x 1KB = 64 KB fragment-packed A

  const int tid = threadIdx.x;
  const int lane = tid & 63, wid = tid >> 6;
  const int bid = blockIdx.x;
  const int mb = ((bid & 7) << 1) | ((bid >> 3) & 1);  // row-cluster (XCD-aligned)
  const int nb = bid >> 4;                             // 16 col slices of 64
  const int rowBase = mb * 32;
  const int colBase = nb * 64;
  const int wr = wid & 1, wc = wid >> 1;
  const int r0 = rowBase + wr * 16 + ((lane >> 4) << 2);
  const int c0 = colBase + wc * 16 + (lane & 15);

  const bf16* whh  = (const bf16*)(ws + WHH_OFF);
  const bf16* fc1w = (const bf16*)(ws + FC1_OFF);
  const bf16* fc2w = (const bf16*)(ws + FC2_OFF);
  const bf16* xp   = (const bf16*)(ws + XP_OFF);
  bf16* hb = (bf16*)(ws + HB_OFF);
  bf16* yl = (bf16*)(ws + EMB_OFF);   // emb dead after xproj
  bf16* y1 = (bf16*)(ws + WIH_OFF);   // w_ih dead after xproj
  unsigned* bar = (unsigned*)(ws + BAR_OFF + (size_t)mb * 128);

  // per-thread invariants hoisted out of the 64-step loop
  const float bhv = b_hh[c0];
  int lenv[4];
#pragma unroll
  for (int reg = 0; reg < 4; ++reg) lenv[reg] = lens[r0 + reg];

  bf16x8 breg[16][2];
  load_breg(breg, whh, c0, lane);

  bf16 xv[4];
#pragma unroll
  for (int reg = 0; reg < 4; ++reg) xv[reg] = xp[(size_t)(r0 + reg) * H_SZ + c0];

#pragma unroll 1
  for (int t = 0; t < S_SZ; ++t) {
    const bf16* hsrc = hb + ((size_t)(t & 3) << 19);
    bf16* hdst = hb + ((size_t)((t + 1) & 3) << 19);
    phase<0>(hsrc, breg, Ap, lane, wid, rowBase, bhv, xv, lenv, t, r0, c0,
             hdst, yl, nullptr);
    if (t < S_SZ - 1) {  // hoist next-step xp fragment; overlaps barrier wait
      const bf16* xpn = xp + (size_t)(t + 1) * (B_SZ * H_SZ);
#pragma unroll
      for (int reg = 0; reg < 4; ++reg)
        xv[reg] = xpn[(size_t)(r0 + reg) * H_SZ + c0];
    }
    clusterbar(bar, (unsigned)(t + 1) * 16u, (t & 3) == 3);
  }

  // FC1 (relu): B = fc1 fragments in regs
  load_breg(breg, fc1w, c0, lane);
  const float b1v = fc1_b[c0];
  phase<1>(yl, breg, Ap, lane, wid, rowBase, b1v, xv, lenv, 0, r0, c0,
           y1, nullptr, nullptr);
  clusterbar(bar, 65u * 16u, true);

  // FC2: B = fc2 fragments (pad rows >=1000 are zeros/counters; those output
  // columns are discarded at the store)
  load_breg(breg, fc2w, c0, lane);
  const float b2v = (c0 < C_SZ) ? fc2_b[c0] : 0.f;
  phase<2>(y1, breg, Ap, lane, wid, rowBase, b2v, xv, lenv, 0, r0, c0,
           nullptr, nullptr, out);
}

// ---------------------------------------------------------------------------
extern "C" void kernel_launch(void* const* d_in, const int* in_sizes, int n_in,
                              void* d_out, int out_size, void* d_ws, size_t ws_size,
                              hipStream_t stream) {
  (void)in_sizes; (void)n_in; (void)out_size; (void)ws_size;
  const int* x_in = (const int*)d_in[0];
  const int* x_len = (const int*)d_in[1];
  const float* emb_w = (const float*)d_in[2];
  const float* w_ih = (const float*)d_in[3];
  const float* b_ih = (const float*)d_in[4];
  const float* w_hh = (const float*)d_in[5];
  const float* b_hh = (const float*)d_in[6];
  const float* fc1_w = (const float*)d_in[7];
  const float* fc1_b = (const float*)d_in[8];
  const float* fc2_w = (const float*)d_in[9];
  const float* fc2_b = (const float*)d_in[10];
  char* ws = (char*)d_ws;
  float* out = (float*)d_out;

  // 1) weights -> bf16, zero h_buf0, zero fc2 pads (incl. barrier counters)
  prep_kernel<<<2048, 256, 0, stream>>>(emb_w, w_ih, w_hh, fc1_w, fc2_w, ws);

  // 2) x_proj GEMM (gathered A)
  xproj_kernel<<<2048, 256, 0, stream>>>(x_in, b_ih, ws);

  // 3) fused RNN + FC1 + FC2: reg-resident B, single-barrier A staging
  rnn_fused_kernel<<<256, 512, 0, stream>>>(b_hh, fc1_b, fc2_b, x_len, ws, out);
}